// Round 6
// baseline (555.597 us; speedup 1.0000x reference)
//
#include <hip/hip_runtime.h>
#include <hip/hip_bf16.h>

// Problem constants (reference: B=1024, F=128, E=256, HEAD_NUM=8, d=32)
// Reference dtypes: ALL fp32 (inputs and output). bf16 internally.
#define B_SZ 1024
#define F_SZ 128
#define E_SZ 256
#define H_NUM 8
#define D_SZ 32

typedef __bf16 bf16x8 __attribute__((ext_vector_type(8)));
typedef float f32x4 __attribute__((ext_vector_type(4)));
typedef unsigned short u16x4 __attribute__((ext_vector_type(4)));

__device__ __forceinline__ bf16x8 frag_at(const __hip_bfloat16* p) {
  return *reinterpret_cast<const bf16x8*>(p);
}

__device__ __forceinline__ bf16x8 pack_bf16x8(float4 a, float4 b) {
  bf16x8 r;
  r[0] = (__bf16)a.x; r[1] = (__bf16)a.y; r[2] = (__bf16)a.z; r[3] = (__bf16)a.w;
  r[4] = (__bf16)b.x; r[5] = (__bf16)b.y; r[6] = (__bf16)b.z; r[7] = (__bf16)b.w;
  return r;
}

__device__ __forceinline__ unsigned short f2bf_bits(float f) {
  __hip_bfloat16 b = __float2bfloat16(f);
  return *reinterpret_cast<unsigned short*>(&b);
}

__device__ __forceinline__ float bf_bits2f(unsigned short u) {
  unsigned int x = ((unsigned int)u) << 16;
  union { unsigned int i; float f; } c; c.i = x;
  return c.f;
}

// ---------------------------------------------------------------------------
// Prep 1: transpose the four fp32 E x E weights into bf16 WT[n][e] (n-major).
// ---------------------------------------------------------------------------
__global__ void transpose_weights(const float* __restrict__ W0,
                                  const float* __restrict__ W1,
                                  const float* __restrict__ W2,
                                  const float* __restrict__ W3,
                                  __hip_bfloat16* __restrict__ WT) {
  __shared__ float tile[64][65];
  const int wsel = blockIdx.x >> 4;
  const float* W = wsel == 0 ? W0 : wsel == 1 ? W1 : wsel == 2 ? W2 : W3;
  __hip_bfloat16* T = WT + wsel * (E_SZ * E_SZ);
  const int t = blockIdx.x & 15;
  const int tr = (t >> 2) * 64, tc = (t & 3) * 64;
  for (int k = 0; k < 16; ++k) {
    int fl = k * 256 + threadIdx.x;
    int lr = fl >> 6, lc = fl & 63;
    tile[lr][lc] = W[(tr + lr) * E_SZ + tc + lc];
  }
  __syncthreads();
  for (int k = 0; k < 16; ++k) {
    int fl = k * 256 + threadIdx.x;
    int lr = fl >> 6, lc = fl & 63;
    T[(tc + lr) * E_SZ + tr + lc] = __float2bfloat16(tile[lc][lr]);
  }
}

// ---------------------------------------------------------------------------
// Prep 2: convert X fp32 -> bf16 (row-major unchanged). ~200 MB traffic.
// ---------------------------------------------------------------------------
__global__ __launch_bounds__(256)
void cvt_x(const float* __restrict__ X, __hip_bfloat16* __restrict__ Xb) {
  size_t i = ((size_t)blockIdx.x * 256 + threadIdx.x) * 8;
  float4 a0 = *reinterpret_cast<const float4*>(X + i);
  float4 a1 = *reinterpret_cast<const float4*>(X + i + 4);
  *reinterpret_cast<bf16x8*>(Xb + i) = pack_bf16x8(a0, a1);
}

// ---------------------------------------------------------------------------
// v5: fused per-batch kernel, occupancy-first.
//  - No X LDS tile: phase P reads X bf16 fragments from global (block's 64 KB
//    slice is L2-resident after head 0). LDS = 74.2 KB -> 2 blocks/CU;
//    __launch_bounds__(512,4) caps VGPR<=128 -> 4 waves/SIMD (2x occupancy).
//  - Operand-SWAPPED MFMAs so the reg-contiguous C dim becomes the store-
//    contiguous dim everywhere:
//      P: D[n][f] = mfma(W-rows, X-rows)  -> u16x4 LDS writes to Q/K/R[f][n]
//         (V uses normal order + transposed u16x4 store to Vt[d][f] as before)
//      S: D[k][f] = mfma(K-rows, Q-rows)  -> softmax row is lane-local
//         (in-lane 32-max + shfl_xor 16/32), u16x4 P writes to Ps[f][k]
//      PV: D[d][f] = mfma(Vt-rows, P-rows) -> ds_read_b64 residual +
//         global_store_dwordx4 out (full 128-B lines per row)
// 2 barriers/head, none in prologue.
// ---------------------------------------------------------------------------
#define QST 40    // Qs/Ks/Rs stride (32 + 8)
#define VST 136   // Vt stride (128 + 8)
#define PST 136   // Ps stride (128 + 8)

#define QS_OFF 0
#define KS_OFF (128 * QST)             // 5120
#define RS_OFF (2 * 128 * QST)         // 10240
#define VT_OFF (3 * 128 * QST)         // 15360
#define PS_OFF (VT_OFF + 32 * VST)     // 19712
#define SMEM_ELEMS (PS_OFF + 128 * PST)  // 37120 elems -> 74240 B

__global__ __launch_bounds__(512, 4)
void fused_attn(const __hip_bfloat16* __restrict__ Xb,
                const __hip_bfloat16* __restrict__ WT,
                float* __restrict__ out) {
  __shared__ __align__(16) __hip_bfloat16 smem[SMEM_ELEMS];
  __hip_bfloat16* const Qs = smem + QS_OFF;
  __hip_bfloat16* const Ks = smem + KS_OFF;
  __hip_bfloat16* const Rs = smem + RS_OFF;
  __hip_bfloat16* const Vt = smem + VT_OFF;
  __hip_bfloat16* const Ps = smem + PS_OFF;

  const int tid  = threadIdx.x;
  const int wave = tid >> 6;          // 0..7
  const int lane = tid & 63;
  const int quad = lane >> 4;
  const int l16  = lane & 15;
  const int b    = blockIdx.x;
  const int fw   = wave * 16;         // this wave's 16 q-rows in phases S/PV

  const int pmat = wave >> 1;         // 0=Q 1=K 2=V 3=R
  const int prh  = wave & 1;          // row half (64 rows) in phase P
  const __hip_bfloat16* Xw = Xb + ((size_t)b * F_SZ + prh * 64) * E_SZ;
  const __hip_bfloat16* Wmat = WT + pmat * (E_SZ * E_SZ);
  __hip_bfloat16* const Pw = Ps + fw * PST;

  for (int h = 0; h < H_NUM; ++h) {
    // ================= Phase P: QKVR head-slice projection =================
    {
      const __hip_bfloat16* Wh = Wmat + (h * D_SZ) * E_SZ;
      f32x4 acc[2][4];
      #pragma unroll
      for (int nt = 0; nt < 2; ++nt)
        #pragma unroll
        for (int mt = 0; mt < 4; ++mt) acc[nt][mt] = f32x4{0.f, 0.f, 0.f, 0.f};

      #pragma unroll
      for (int ks = 0; ks < 8; ++ks) {
        const int ko = ks * 32 + quad * 8;
        bf16x8 aw0 = frag_at(Wh + l16 * E_SZ + ko);         // n rows 0..15
        bf16x8 aw1 = frag_at(Wh + (16 + l16) * E_SZ + ko);  // n rows 16..31
        #pragma unroll
        for (int mt = 0; mt < 4; ++mt) {
          bf16x8 ax = frag_at(Xw + (mt * 16 + l16) * E_SZ + ko);
          if (pmat != 2) {   // swapped: D[n][f]
            acc[0][mt] = __builtin_amdgcn_mfma_f32_16x16x32_bf16(aw0, ax, acc[0][mt], 0, 0, 0);
            acc[1][mt] = __builtin_amdgcn_mfma_f32_16x16x32_bf16(aw1, ax, acc[1][mt], 0, 0, 0);
          } else {           // normal: D[f][n] (for transposed Vt store)
            acc[0][mt] = __builtin_amdgcn_mfma_f32_16x16x32_bf16(ax, aw0, acc[0][mt], 0, 0, 0);
            acc[1][mt] = __builtin_amdgcn_mfma_f32_16x16x32_bf16(ax, aw1, acc[1][mt], 0, 0, 0);
          }
        }
      }
      if (pmat != 2) {
        // D[n][f]: row(n_local)=quad*4+reg, col(f_local)=l16.
        // Store T[f][n]: regs contiguous along n -> u16x4.
        __hip_bfloat16* T = (pmat == 0) ? Qs : (pmat == 1) ? Ks : Rs;
        #pragma unroll
        for (int nt = 0; nt < 2; ++nt)
          #pragma unroll
          for (int mt = 0; mt < 4; ++mt) {
            u16x4 pk;
            #pragma unroll
            for (int reg = 0; reg < 4; ++reg) pk[reg] = f2bf_bits(acc[nt][mt][reg]);
            *reinterpret_cast<u16x4*>(
                &T[(prh * 64 + mt * 16 + l16) * QST + nt * 16 + quad * 4]) = pk;
          }
      } else {
        // D[f][n]: row(f_local)=quad*4+reg, col(d_local)=l16.
        // Store Vt[d][f]: regs contiguous along f -> u16x4.
        #pragma unroll
        for (int nt = 0; nt < 2; ++nt)
          #pragma unroll
          for (int mt = 0; mt < 4; ++mt) {
            u16x4 pk;
            #pragma unroll
            for (int reg = 0; reg < 4; ++reg) pk[reg] = f2bf_bits(acc[nt][mt][reg]);
            *reinterpret_cast<u16x4*>(
                &Vt[(nt * 16 + l16) * VST + prh * 64 + mt * 16 + quad * 4]) = pk;
          }
      }
    }
    __syncthreads();

    // ====== Phase S (swapped): S^T tiles, lane-local softmax, P -> LDS =====
    {
      bf16x8 bq = frag_at(&Qs[(fw + l16) * QST + quad * 8]);   // Q rows = B
      f32x4 s[8];
      #pragma unroll
      for (int nt = 0; nt < 8; ++nt) {
        bf16x8 ak = frag_at(&Ks[(nt * 16 + l16) * QST + quad * 8]);  // K rows = A
        s[nt] = __builtin_amdgcn_mfma_f32_16x16x32_bf16(
            ak, bq, f32x4{0.f, 0.f, 0.f, 0.f}, 0, 0, 0);
      }
      // lane holds S[f = fw+l16][k = nt*16 + quad*4 + reg] (32 values)
      float m = s[0][0];
      #pragma unroll
      for (int nt = 0; nt < 8; ++nt)
        #pragma unroll
        for (int reg = 0; reg < 4; ++reg) m = fmaxf(m, s[nt][reg]);
      m = fmaxf(m, __shfl_xor(m, 16));
      m = fmaxf(m, __shfl_xor(m, 32));
      float sum = 0.f;
      #pragma unroll
      for (int nt = 0; nt < 8; ++nt)
        #pragma unroll
        for (int reg = 0; reg < 4; ++reg) {
          float e = __expf(s[nt][reg] - m);
          s[nt][reg] = e;
          sum += e;
        }
      sum += __shfl_xor(sum, 16);
      sum += __shfl_xor(sum, 32);
      const float inv = 1.f / sum;
      #pragma unroll
      for (int nt = 0; nt < 8; ++nt) {
        u16x4 pk;
        #pragma unroll
        for (int reg = 0; reg < 4; ++reg) pk[reg] = f2bf_bits(s[nt][reg] * inv);
        *reinterpret_cast<u16x4*>(&Pw[l16 * PST + nt * 16 + quad * 4]) = pk;
      }
    }

    // ====== Phase PV (swapped): O^T = Vt P^T, fused residual/relu ==========
    {
      f32x4 o[2];
      o[0] = f32x4{0.f, 0.f, 0.f, 0.f};
      o[1] = f32x4{0.f, 0.f, 0.f, 0.f};
      #pragma unroll
      for (int ks = 0; ks < 4; ++ks) {
        const int ko = ks * 32 + quad * 8;
        bf16x8 bp  = *reinterpret_cast<const bf16x8*>(Pw + l16 * PST + ko);  // P rows = B
        bf16x8 av0 = frag_at(&Vt[l16 * VST + ko]);          // Vt rows d 0..15 = A
        bf16x8 av1 = frag_at(&Vt[(16 + l16) * VST + ko]);   // d 16..31
        o[0] = __builtin_amdgcn_mfma_f32_16x16x32_bf16(av0, bp, o[0], 0, 0, 0);
        o[1] = __builtin_amdgcn_mfma_f32_16x16x32_bf16(av1, bp, o[1], 0, 0, 0);
      }
      // lane holds O[f = fw+l16][d = nt*16 + quad*4 + reg]
      const size_t orow = ((size_t)b * F_SZ + fw + l16) * E_SZ + h * D_SZ;
      #pragma unroll
      for (int nt = 0; nt < 2; ++nt) {
        u16x4 rv = *reinterpret_cast<const u16x4*>(
            &Rs[(fw + l16) * QST + nt * 16 + quad * 4]);
        float4 st;
        float v0 = o[nt][0] + bf_bits2f(rv[0]);
        float v1 = o[nt][1] + bf_bits2f(rv[1]);
        float v2 = o[nt][2] + bf_bits2f(rv[2]);
        float v3 = o[nt][3] + bf_bits2f(rv[3]);
        st.x = (v0 < 0.f) ? 0.f : v0;
        st.y = (v1 < 0.f) ? 0.f : v1;
        st.z = (v2 < 0.f) ? 0.f : v2;
        st.w = (v3 < 0.f) ? 0.f : v3;
        *reinterpret_cast<float4*>(&out[orow + nt * 16 + quad * 4]) = st;
      }
    }
    __syncthreads();
  }
}

// ---------------------------------------------------------------------------
extern "C" void kernel_launch(void* const* d_in, const int* in_sizes, int n_in,
                              void* d_out, int out_size, void* d_ws, size_t ws_size,
                              hipStream_t stream) {
  const float* X  = (const float*)d_in[0];
  const float* Wq = (const float*)d_in[1];
  const float* Wk = (const float*)d_in[2];
  const float* Wv = (const float*)d_in[3];
  const float* Wr = (const float*)d_in[4];
  float* out = (float*)d_out;

  char* ws = (char*)d_ws;
  __hip_bfloat16* WT = (__hip_bfloat16*)ws;                     // 512 KB
  __hip_bfloat16* Xb = (__hip_bfloat16*)(ws + 512 * 1024);      // 64 MB

  (void)hipGetLastError();  // clear stale error state
  transpose_weights<<<64, 256, 0, stream>>>(Wq, Wk, Wv, Wr, WT);
  cvt_x<<<(B_SZ * F_SZ * E_SZ / 8) / 256, 256, 0, stream>>>(X, Xb);
  fused_attn<<<B_SZ, 512, 0, stream>>>(Xb, WT, out);

  // Launch-failure exfiltration (no-op when launches succeed).
  hipError_t err = hipGetLastError();
  if (err != hipSuccess) {
    hipMemsetAsync(d_out, 0x7F, 1024, stream);
  }
}

// Round 7
// 484.618 us; speedup vs baseline: 1.1465x; 1.1465x over previous
//
#include <hip/hip_runtime.h>
#include <hip/hip_bf16.h>

// Problem constants (reference: B=1024, F=128, E=256, HEAD_NUM=8, d=32)
// Reference dtypes: ALL fp32 (inputs and output). bf16 internally.
#define B_SZ 1024
#define F_SZ 128
#define E_SZ 256
#define H_NUM 8
#define D_SZ 32

typedef __bf16 bf16x8 __attribute__((ext_vector_type(8)));
typedef float f32x4 __attribute__((ext_vector_type(4)));
typedef unsigned short u16x4 __attribute__((ext_vector_type(4)));

__device__ __forceinline__ bf16x8 frag_at(const __hip_bfloat16* p) {
  return *reinterpret_cast<const bf16x8*>(p);
}

__device__ __forceinline__ bf16x8 pack_bf16x8(float4 a, float4 b) {
  bf16x8 r;
  r[0] = (__bf16)a.x; r[1] = (__bf16)a.y; r[2] = (__bf16)a.z; r[3] = (__bf16)a.w;
  r[4] = (__bf16)b.x; r[5] = (__bf16)b.y; r[6] = (__bf16)b.z; r[7] = (__bf16)b.w;
  return r;
}

__device__ __forceinline__ unsigned short f2bf_bits(float f) {
  __hip_bfloat16 b = __float2bfloat16(f);
  return *reinterpret_cast<unsigned short*>(&b);
}

__device__ __forceinline__ float bf_bits2f(unsigned short u) {
  unsigned int x = ((unsigned int)u) << 16;
  union { unsigned int i; float f; } c; c.i = x;
  return c.f;
}

// ---------------------------------------------------------------------------
// Prep: transpose the four fp32 E x E weights into bf16 WT[n][e] (n-major).
// ---------------------------------------------------------------------------
__global__ void transpose_weights(const float* __restrict__ W0,
                                  const float* __restrict__ W1,
                                  const float* __restrict__ W2,
                                  const float* __restrict__ W3,
                                  __hip_bfloat16* __restrict__ WT) {
  __shared__ float tile[64][65];
  const int wsel = blockIdx.x >> 4;
  const float* W = wsel == 0 ? W0 : wsel == 1 ? W1 : wsel == 2 ? W2 : W3;
  __hip_bfloat16* T = WT + wsel * (E_SZ * E_SZ);
  const int t = blockIdx.x & 15;
  const int tr = (t >> 2) * 64, tc = (t & 3) * 64;
  for (int k = 0; k < 16; ++k) {
    int fl = k * 256 + threadIdx.x;
    int lr = fl >> 6, lc = fl & 63;
    tile[lr][lc] = W[(tr + lr) * E_SZ + tc + lc];
  }
  __syncthreads();
  for (int k = 0; k < 16; ++k) {
    int fl = k * 256 + threadIdx.x;
    int lr = fl >> 6, lc = fl & 63;
    T[(tc + lr) * E_SZ + tr + lc] = __float2bfloat16(tile[lc][lr]);
  }
}

// ---------------------------------------------------------------------------
// v6: fused per-batch kernel with producer/consumer wave specialization.
//  Evidence: v4 (X in LDS) = optimal HBM traffic (74 MB) but 23% occupancy;
//  v5 (X from global) = 44% occupancy but 663 MB fetch (X re-read per head,
//  L2/L3 thrash). v6 keeps BOTH: X staged once in LDS AND 16 waves
//  (4/SIMD): waves 0-7 consume (S/softmax/PV/epilogue for head h), waves
//  8-15 produce (project Q/K/V/R for head h+1). MFMA and VALU pipes
//  co-schedule across waves (m114).
//  Buffering: Vt/Rs double-buffered (written phase A, read phase B of the
//  NEXT head); Qs/Ks single-buffered (consumers read them in phase A,
//  producers overwrite in phase B after the barrier). 2 barriers/head.
//  Consumer math = v5's verified swapped-MFMA path, unchanged.
//  LDS = 158,720 B -> 1 block/CU, 16 waves.
//  X staged fp32->bf16 directly in prologue (cvt_x dispatch dropped).
// ---------------------------------------------------------------------------
#define XST 264   // Xs stride (256+8): row 528 B, 2-way banks max
#define QST 40    // Qs/Ks stride (32+8): row 80 B, 16-B aligned (b128 reads)
#define RST 36    // Rs stride (32+4): row 72 B, 8-B aligned (u16x4 only)
#define VST 136   // Vt stride (128+8)
#define PST 136   // Ps stride (128+8)

#define XS_OFF 0
#define QS_OFF (128 * XST)                   // 33792
#define KS_OFF (QS_OFF + 128 * QST)          // 38912
#define RS_OFF (KS_OFF + 128 * QST)          // 44032 (+ buf*128*RST)
#define VT_OFF (RS_OFF + 2 * 128 * RST)      // 53248 (+ buf*32*VST)
#define PS_OFF (VT_OFF + 2 * 32 * VST)       // 61952
#define SMEM_ELEMS (PS_OFF + 8 * 16 * PST)   // 79360 elems = 158720 B

// Project a 32-row x 32-col head-slice tile of one matrix.
//  vmode=false (Q/K/R): swapped mfma(W,X) -> D[n][f]; store dst[f][n] u16x4.
//  vmode=true  (V):     normal mfma(X,W) -> D[f][n]; store dst[d][f] u16x4.
__device__ __forceinline__ void proj32(
    const __hip_bfloat16* __restrict__ Wmat,
    const __hip_bfloat16* Xs,
    __hip_bfloat16* dst, int dstride, bool vmode,
    int qt, int h, int quad, int l16) {
  const __hip_bfloat16* Wh = Wmat + (h * D_SZ) * E_SZ;
  f32x4 acc[2][2];
  #pragma unroll
  for (int nt = 0; nt < 2; ++nt)
    #pragma unroll
    for (int mt = 0; mt < 2; ++mt) acc[nt][mt] = f32x4{0.f, 0.f, 0.f, 0.f};

  #pragma unroll
  for (int ks = 0; ks < 8; ++ks) {
    const int ko = ks * 32 + quad * 8;
    bf16x8 aw0 = frag_at(Wh + l16 * E_SZ + ko);         // n rows 0..15
    bf16x8 aw1 = frag_at(Wh + (16 + l16) * E_SZ + ko);  // n rows 16..31
    #pragma unroll
    for (int mt = 0; mt < 2; ++mt) {
      bf16x8 ax = frag_at(&Xs[(qt * 32 + mt * 16 + l16) * XST + ko]);
      if (!vmode) {
        acc[0][mt] = __builtin_amdgcn_mfma_f32_16x16x32_bf16(aw0, ax, acc[0][mt], 0, 0, 0);
        acc[1][mt] = __builtin_amdgcn_mfma_f32_16x16x32_bf16(aw1, ax, acc[1][mt], 0, 0, 0);
      } else {
        acc[0][mt] = __builtin_amdgcn_mfma_f32_16x16x32_bf16(ax, aw0, acc[0][mt], 0, 0, 0);
        acc[1][mt] = __builtin_amdgcn_mfma_f32_16x16x32_bf16(ax, aw1, acc[1][mt], 0, 0, 0);
      }
    }
  }
  if (!vmode) {
    // D[n][f]: row(n)=quad*4+reg, col(f)=l16 -> dst[f][n], regs along n.
    #pragma unroll
    for (int nt = 0; nt < 2; ++nt)
      #pragma unroll
      for (int mt = 0; mt < 2; ++mt) {
        u16x4 pk;
        #pragma unroll
        for (int reg = 0; reg < 4; ++reg) pk[reg] = f2bf_bits(acc[nt][mt][reg]);
        *reinterpret_cast<u16x4*>(
            &dst[(qt * 32 + mt * 16 + l16) * dstride + nt * 16 + quad * 4]) = pk;
      }
  } else {
    // D[f][n]: row(f)=quad*4+reg, col(d)=l16 -> Vt[d][f], regs along f.
    #pragma unroll
    for (int nt = 0; nt < 2; ++nt)
      #pragma unroll
      for (int mt = 0; mt < 2; ++mt) {
        u16x4 pk;
        #pragma unroll
        for (int reg = 0; reg < 4; ++reg) pk[reg] = f2bf_bits(acc[nt][mt][reg]);
        *reinterpret_cast<u16x4*>(
            &dst[(nt * 16 + l16) * dstride + qt * 32 + mt * 16 + quad * 4]) = pk;
      }
  }
}

__global__ __launch_bounds__(1024, 4)
void fused_attn(const float* __restrict__ X,
                const __hip_bfloat16* __restrict__ WT,
                float* __restrict__ out) {
  __shared__ __align__(16) __hip_bfloat16 smem[SMEM_ELEMS];
  __hip_bfloat16* const Xs = smem + XS_OFF;
  __hip_bfloat16* const Qs = smem + QS_OFF;
  __hip_bfloat16* const Ks = smem + KS_OFF;

  const int tid  = threadIdx.x;
  const int wave = tid >> 6;          // 0..15
  const int lane = tid & 63;
  const int quad = lane >> 4;
  const int l16  = lane & 15;
  const int b    = blockIdx.x;

  // ---- prologue 1: stage X_b (fp32 -> bf16) into LDS, coalesced
  const float* Xb = X + (size_t)b * (F_SZ * E_SZ);
  #pragma unroll
  for (int i = 0; i < 4; ++i) {
    int ch = i * 1024 + tid;          // 4096 chunks of 8 floats
    int r = ch >> 5, c = ch & 31;
    const float* sa = Xb + r * E_SZ + c * 8;
    float4 a0 = *reinterpret_cast<const float4*>(sa);
    float4 a1 = *reinterpret_cast<const float4*>(sa + 4);
    *reinterpret_cast<bf16x8*>(&Xs[r * XST + c * 8]) = pack_bf16x8(a0, a1);
  }
  __syncthreads();

  // ---- prologue 2: all 16 waves project head 0 (4 mats x 4 row-quarters)
  {
    const int mat = wave >> 2;        // 0=Q 1=K 2=V 3=R
    const int qt  = wave & 3;
    __hip_bfloat16* dst = (mat == 0) ? Qs
                        : (mat == 1) ? Ks
                        : (mat == 2) ? (smem + VT_OFF)          // Vt buf0
                                     : (smem + RS_OFF);         // Rs buf0
    const int stride = (mat == 2) ? VST : (mat == 3) ? RST : QST;
    proj32(WT + mat * (E_SZ * E_SZ), Xs, dst, stride, mat == 2,
           qt, 0, quad, l16);
  }
  __syncthreads();

  const int fw = (wave & 7) * 16;     // consumer q-row block
  __hip_bfloat16* const Pw = smem + PS_OFF + fw * PST;
  const int pi = wave - 8;            // producer index 0..7

  for (int h = 0; h < H_NUM; ++h) {
    const int nbuf = (h + 1) & 1;
    // ================= Phase A =================
    if (wave < 8) {
      // Consumer: S^T = mfma(K,Q), lane-local softmax, P -> own LDS slice
      bf16x8 bq = frag_at(&Qs[(fw + l16) * QST + quad * 8]);
      f32x4 s[8];
      #pragma unroll
      for (int nt = 0; nt < 8; ++nt) {
        bf16x8 ak = frag_at(&Ks[(nt * 16 + l16) * QST + quad * 8]);
        s[nt] = __builtin_amdgcn_mfma_f32_16x16x32_bf16(
            ak, bq, f32x4{0.f, 0.f, 0.f, 0.f}, 0, 0, 0);
      }
      // lane holds S[f = fw+l16][k = nt*16 + quad*4 + reg] (32 values)
      float m = s[0][0];
      #pragma unroll
      for (int nt = 0; nt < 8; ++nt)
        #pragma unroll
        for (int reg = 0; reg < 4; ++reg) m = fmaxf(m, s[nt][reg]);
      m = fmaxf(m, __shfl_xor(m, 16));
      m = fmaxf(m, __shfl_xor(m, 32));
      float sum = 0.f;
      #pragma unroll
      for (int nt = 0; nt < 8; ++nt)
        #pragma unroll
        for (int reg = 0; reg < 4; ++reg) {
          float e = __expf(s[nt][reg] - m);
          s[nt][reg] = e;
          sum += e;
        }
      sum += __shfl_xor(sum, 16);
      sum += __shfl_xor(sum, 32);
      const float inv = 1.f / sum;
      #pragma unroll
      for (int nt = 0; nt < 8; ++nt) {
        u16x4 pk;
        #pragma unroll
        for (int reg = 0; reg < 4; ++reg) pk[reg] = f2bf_bits(s[nt][reg] * inv);
        *reinterpret_cast<u16x4*>(&Pw[l16 * PST + nt * 16 + quad * 4]) = pk;
      }
    } else if (h < H_NUM - 1) {
      // Producer: V (pi 0-3) / R (pi 4-7) for head h+1 into buf nbuf
      const int mat = (pi < 4) ? 2 : 3;
      __hip_bfloat16* dst = (mat == 2) ? (smem + VT_OFF + nbuf * 32 * VST)
                                       : (smem + RS_OFF + nbuf * 128 * RST);
      proj32(WT + mat * (E_SZ * E_SZ), Xs, dst,
             (mat == 2) ? VST : RST, mat == 2, pi & 3, h + 1, quad, l16);
    }
    __syncthreads();

    // ================= Phase B =================
    if (wave < 8) {
      // Consumer: O^T = mfma(Vt, P), fused residual/relu epilogue
      const __hip_bfloat16* Vtb = smem + VT_OFF + (h & 1) * 32 * VST;
      const __hip_bfloat16* Rsb = smem + RS_OFF + (h & 1) * 128 * RST;
      f32x4 o[2];
      o[0] = f32x4{0.f, 0.f, 0.f, 0.f};
      o[1] = f32x4{0.f, 0.f, 0.f, 0.f};
      #pragma unroll
      for (int ks = 0; ks < 4; ++ks) {
        const int ko = ks * 32 + quad * 8;
        bf16x8 bp  = *reinterpret_cast<const bf16x8*>(Pw + l16 * PST + ko);
        bf16x8 av0 = frag_at(&Vtb[l16 * VST + ko]);
        bf16x8 av1 = frag_at(&Vtb[(16 + l16) * VST + ko]);
        o[0] = __builtin_amdgcn_mfma_f32_16x16x32_bf16(av0, bp, o[0], 0, 0, 0);
        o[1] = __builtin_amdgcn_mfma_f32_16x16x32_bf16(av1, bp, o[1], 0, 0, 0);
      }
      // lane holds O[f = fw+l16][d = nt*16 + quad*4 + reg]
      const size_t orow = ((size_t)b * F_SZ + fw + l16) * E_SZ + h * D_SZ;
      #pragma unroll
      for (int nt = 0; nt < 2; ++nt) {
        u16x4 rv = *reinterpret_cast<const u16x4*>(
            &Rsb[(fw + l16) * RST + nt * 16 + quad * 4]);
        float4 st;
        float v0 = o[nt][0] + bf_bits2f(rv[0]);
        float v1 = o[nt][1] + bf_bits2f(rv[1]);
        float v2 = o[nt][2] + bf_bits2f(rv[2]);
        float v3 = o[nt][3] + bf_bits2f(rv[3]);
        st.x = (v0 < 0.f) ? 0.f : v0;
        st.y = (v1 < 0.f) ? 0.f : v1;
        st.z = (v2 < 0.f) ? 0.f : v2;
        st.w = (v3 < 0.f) ? 0.f : v3;
        *reinterpret_cast<float4*>(&out[orow + nt * 16 + quad * 4]) = st;
      }
    } else if (h < H_NUM - 1) {
      // Producer: Q (pi 0-3) / K (pi 4-7) for head h+1 (single-buffered;
      // consumers finished reading them in phase A of head h)
      const int mat = (pi < 4) ? 0 : 1;
      proj32(WT + mat * (E_SZ * E_SZ), Xs, (mat == 0) ? Qs : Ks,
             QST, false, pi & 3, h + 1, quad, l16);
    }
    __syncthreads();
  }
}

// ---------------------------------------------------------------------------
extern "C" void kernel_launch(void* const* d_in, const int* in_sizes, int n_in,
                              void* d_out, int out_size, void* d_ws, size_t ws_size,
                              hipStream_t stream) {
  const float* X  = (const float*)d_in[0];
  const float* Wq = (const float*)d_in[1];
  const float* Wk = (const float*)d_in[2];
  const float* Wv = (const float*)d_in[3];
  const float* Wr = (const float*)d_in[4];
  float* out = (float*)d_out;

  __hip_bfloat16* WT = (__hip_bfloat16*)d_ws;   // 4*256*256*2 = 512 KB

  (void)hipGetLastError();  // clear stale error state
  transpose_weights<<<64, 256, 0, stream>>>(Wq, Wk, Wv, Wr, WT);
  fused_attn<<<B_SZ, 1024, 0, stream>>>(X, WT, out);

  // Launch-failure exfiltration (no-op when launches succeed).
  hipError_t err = hipGetLastError();
  if (err != hipSuccess) {
    hipMemsetAsync(d_out, 0x7F, 1024, stream);
  }
}